// Round 1
// baseline (557.450 us; speedup 1.0000x reference)
//
#include <hip/hip_runtime.h>
#include <math.h>

#define NS   16
#define HH   512
#define WW   512
#define HW   (HH*WW)
#define TOPK 13107

// ws element offsets (32-bit words)
#define O_O1   0        // [16][7] squashed o1 params
#define O_O2   112      // [16][4] softmax weights
#define O_DEN  176      // [16]    sum(o2)+0.001
#define O_MINB 192      // [48]    per (n,c) min (float bits, int atomics)
#define O_MAXB 240      // [48]
#define O_PFX  288      // [16]    radix-select prefix (u32)
#define O_KN   304      // [16]    remaining k
#define O_SGT  320      // [16][3] sum x where dark >  vk
#define O_SEQ  368      // [16][3] sum x where dark == vk
#define O_CEQ  416      // [16]    count dark == vk (as float)
#define O_HIST 432      // [16][2048] u32
#define O_DARK 33280    // [16*512*512] f32 dark channel

__device__ __forceinline__ float tanh01(float v) { return tanhf(v)*0.5f + 0.5f; }
__device__ __forceinline__ float clamp01(float v) { return fminf(fmaxf(v, 0.0f), 1.0f); }

// ---------------- params + state init ----------------
__global__ void k_params(const float* __restrict__ o1, const float* __restrict__ o2,
                         float* __restrict__ wsf, unsigned* __restrict__ wsu) {
  int tid = threadIdx.x;
  for (int i = tid; i < NS*2048; i += 256) wsu[O_HIST + i] = 0u;
  if (tid < 48) {
    wsu[O_MINB + tid] = 0x7F800000u;  // +inf
    wsu[O_MAXB + tid] = 0u;           // 0.0f
    wsf[O_SGT + tid] = 0.0f;
    wsf[O_SEQ + tid] = 0.0f;
  }
  if (tid < NS) {
    wsf[O_CEQ + tid] = 0.0f;
    wsu[O_PFX + tid] = 0u;
    wsu[O_KN  + tid] = (unsigned)TOPK;
    int n = tid;
    float p0 = tanh01(o1[n*7+0])*0.25f + 1.0f;
    float p1 = tanh01(o1[n*7+1])*0.9f  + 0.1f;
    float p2 = tanh01(o1[n*7+2])*2.0f;
    float p3 = tanh01(o1[n*7+3]);
    float p4 = tanh01(o1[n*7+4])*0.1f + 0.95f;
    float p5 = tanh01(o1[n*7+5])*0.1f + 0.95f;
    float p6 = tanh01(o1[n*7+6])*0.1f + 0.95f;
    wsf[O_O1+n*7+0]=p0; wsf[O_O1+n*7+1]=p1; wsf[O_O1+n*7+2]=p2; wsf[O_O1+n*7+3]=p3;
    wsf[O_O1+n*7+4]=p4; wsf[O_O1+n*7+5]=p5; wsf[O_O1+n*7+6]=p6;
    float e0 = expf(tanh01(o2[n*4+0]));
    float e1 = expf(tanh01(o2[n*4+1]));
    float e2 = expf(tanh01(o2[n*4+2]));
    float e3 = expf(tanh01(o2[n*4+3]));
    float s = e0+e1+e2+e3;
    float q0 = e0/s, q1 = e1/s, q2 = e2/s, q3 = e3/s;
    wsf[O_O2+n*4+0]=q0; wsf[O_O2+n*4+1]=q1; wsf[O_O2+n*4+2]=q2; wsf[O_O2+n*4+3]=q3;
    wsf[O_DEN+n] = (q0+q1+q2+q3) + 0.001f;
  }
}

// ---------------- minc + horizontal 15-tap box sum ----------------
__global__ void k_rowsum(const float* __restrict__ x, float* __restrict__ rowsum) {
  int h = blockIdx.x, n = blockIdx.y, tid = threadIdx.x;
  __shared__ float m[WW + 14];
  const float* x0 = x + (size_t)(n*3+0)*HW + (size_t)h*WW;
  const float* x1 = x + (size_t)(n*3+1)*HW + (size_t)h*WW;
  const float* x2 = x + (size_t)(n*3+2)*HW + (size_t)h*WW;
  if (tid < 7) { m[tid] = 0.0f; m[519 + tid] = 0.0f; }
  for (int w = tid; w < WW; w += 256)
    m[7 + w] = fminf(fminf(x0[w], x1[w]), x2[w]);
  __syncthreads();
  float* rs = rowsum + (size_t)n*HW + (size_t)h*WW;
  for (int w = tid; w < WW; w += 256) {
    float s = 0.0f;
    #pragma unroll
    for (int j = 0; j < 15; ++j) s += m[w + j];
    rs[w] = s;
  }
}

// ---------------- vertical 15-tap sliding sum -> dark ----------------
__global__ void k_colsum(const float* __restrict__ rowsum, float* __restrict__ wsf) {
  int w  = blockIdx.x * 256 + threadIdx.x;
  int h0 = blockIdx.y * 32;
  int n  = blockIdx.z;
  const float* rs = rowsum + (size_t)n*HW;
  float* dk = wsf + O_DARK + (size_t)n*HW;
  float s = 0.0f;
  #pragma unroll
  for (int dh = -7; dh <= 7; ++dh) {
    int h = h0 + dh;
    if (h >= 0 && h < HH) s += rs[h*WW + w];
  }
  for (int h = h0; h < h0 + 32; ++h) {
    dk[h*WW + w] = s * (1.0f/225.0f);
    int ha = h + 8, hr = h - 7;
    float va = (ha < HH) ? rs[ha*WW + w] : 0.0f;
    float vr = (hr >= 0) ? rs[hr*WW + w] : 0.0f;
    s += va - vr;
  }
}

// ---------------- radix-select histogram pass ----------------
__global__ void k_hist(const float* __restrict__ wsf_dark, unsigned* __restrict__ wsu, int pass) {
  int tid = threadIdx.x;
  int n = blockIdx.x >> 6, chunk = blockIdx.x & 63;
  __shared__ unsigned lh[2048];
  for (int i = tid; i < 2048; i += 256) lh[i] = 0u;
  __syncthreads();
  unsigned pfx = wsu[O_PFX + n];
  const unsigned* db = (const unsigned*)(wsf_dark + O_DARK) + (size_t)n*HW + (size_t)chunk*4096;
  int lane = tid & 63;
  for (int k = 0; k < 16; ++k) {
    unsigned b = db[k*256 + tid];
    bool need; unsigned bin;
    if (pass == 0)      { need = true;                          bin = b >> 21; }
    else if (pass == 1) { need = ((b >> 21) == (pfx >> 21));    bin = (b >> 10) & 0x7FFu; }
    else                { need = ((b >> 10) == (pfx >> 10));    bin = b & 0x3FFu; }
    // wave-aggregated LDS atomics (few distinct bins per wave)
    while (__any(need)) {
      unsigned long long mn = __ballot(need);
      int src = __ffsll((unsigned long long)mn) - 1;
      unsigned bsel = __shfl(bin, src);
      bool same = need && (bin == bsel);
      unsigned long long mm = __ballot(same);
      if (lane == src) atomicAdd(&lh[bsel], (unsigned)__popcll(mm));
      if (same) need = false;
    }
  }
  __syncthreads();
  unsigned* gh = wsu + O_HIST + n*2048;
  for (int i = tid; i < 2048; i += 256) { unsigned v = lh[i]; if (v) atomicAdd(&gh[i], v); }
}

// ---------------- radix-select bin choose ----------------
__global__ void k_select(unsigned* __restrict__ wsu, int pass) {
  int n = blockIdx.x, tid = threadIdx.x;
  int nbins = (pass == 2) ? 1024 : 2048;
  int shift = (pass == 0) ? 21 : (pass == 1) ? 10 : 0;
  unsigned* gh = wsu + O_HIST + n*2048;
  __shared__ unsigned lh[2048];
  __shared__ unsigned partial[256];
  for (int i = tid; i < nbins; i += 256) lh[i] = gh[i];
  __syncthreads();
  int ch = nbins >> 8;
  unsigned ps = 0;
  for (int j = 0; j < ch; ++j) ps += lh[tid*ch + j];
  partial[tid] = ps;
  __syncthreads();
  if (tid == 0) {
    unsigned kn = wsu[O_KN + n];
    unsigned cumAbove = 0; int chunkI = 0;
    for (int t = 255; t >= 0; --t) {
      if (cumAbove + partial[t] >= kn) { chunkI = t; break; }
      cumAbove += partial[t];
    }
    int bsel = chunkI*ch;
    for (int b = chunkI*ch + ch - 1; b >= chunkI*ch; --b) {
      if (cumAbove + lh[b] >= kn) { bsel = b; break; }
      cumAbove += lh[b];
    }
    wsu[O_PFX + n] |= ((unsigned)bsel) << shift;
    wsu[O_KN + n] = kn - cumAbove;
  }
  __syncthreads();
  for (int i = tid; i < nbins; i += 256) gh[i] = 0u;  // ready for next pass
}

// ---------------- atmospheric-light sums ----------------
__global__ void k_asum(const float* __restrict__ x, float* __restrict__ wsf,
                       const unsigned* __restrict__ wsu) {
  int tid = threadIdx.x;
  int n = blockIdx.x >> 6, chunk = blockIdx.x & 63;
  unsigned vk = wsu[O_PFX + n];
  const unsigned* db = (const unsigned*)(wsf + O_DARK) + (size_t)n*HW + (size_t)chunk*4096;
  const float* xb = x + (size_t)n*3*HW + (size_t)chunk*4096;
  float s0=0,s1=0,s2=0,e0=0,e1=0,e2=0,ec=0;
  for (int k = 0; k < 16; ++k) {
    int idx = k*256 + tid;
    unsigned b = db[idx];
    if (b > vk) {
      s0 += xb[idx]; s1 += xb[HW + idx]; s2 += xb[2*HW + idx];
    } else if (b == vk) {
      e0 += xb[idx]; e1 += xb[HW + idx]; e2 += xb[2*HW + idx]; ec += 1.0f;
    }
  }
  #pragma unroll
  for (int off = 32; off; off >>= 1) {
    s0 += __shfl_down(s0, off); s1 += __shfl_down(s1, off); s2 += __shfl_down(s2, off);
    e0 += __shfl_down(e0, off); e1 += __shfl_down(e1, off); e2 += __shfl_down(e2, off);
    ec += __shfl_down(ec, off);
  }
  if ((tid & 63) == 0) {
    atomicAdd(&wsf[O_SGT + n*3 + 0], s0);
    atomicAdd(&wsf[O_SGT + n*3 + 1], s1);
    atomicAdd(&wsf[O_SGT + n*3 + 2], s2);
    atomicAdd(&wsf[O_SEQ + n*3 + 0], e0);
    atomicAdd(&wsf[O_SEQ + n*3 + 1], e1);
    atomicAdd(&wsf[O_SEQ + n*3 + 2], e2);
    atomicAdd(&wsf[O_CEQ + n], ec);
  }
}

// ---------------- fused per-pixel kernel ----------------
__global__ void __launch_bounds__(256)
k_main(const float* __restrict__ x, float* __restrict__ wsf,
       unsigned* __restrict__ wsu, float* __restrict__ out) {
  int tid = threadIdx.x;
  int w0 = blockIdx.x * 64, h0 = blockIdx.y * 16;
  int z = blockIdx.z, n = z / 3, c = z % 3;
  const float* dark = wsf + O_DARK + (size_t)n*HW;
  const float* xc = x + (size_t)z*HW;
  __shared__ float xs[20][68];
  __shared__ float hb[20][64];
  for (int i = tid; i < 20*68; i += 256) {
    int r = i / 68, cc = i - r*68;
    int gh = h0 - 2 + r, gw = w0 - 2 + cc;
    float v = 0.0f;
    if (gh >= 0 && gh < HH && gw >= 0 && gw < WW) v = xc[gh*WW + gw];
    xs[r][cc] = v;
  }
  float g[5];
  {
    float s = 0.0f;
    #pragma unroll
    for (int j = 0; j < 5; ++j) { float d = (float)(j-2); g[j] = expf(-0.5f*d*d); s += g[j]; }
    s += 0.001f;
    #pragma unroll
    for (int j = 0; j < 5; ++j) g[j] /= s;
  }
  __syncthreads();
  for (int i = tid; i < 20*64; i += 256) {
    int r = i >> 6, cc = i & 63;
    hb[r][cc] = xs[r][cc]*g[0] + xs[r][cc+1]*g[1] + xs[r][cc+2]*g[2]
              + xs[r][cc+3]*g[3] + xs[r][cc+4]*g[4];
  }
  __syncthreads();
  float param = wsf[O_O1 + n*7 + 0];
  float lamda = wsf[O_O1 + n*7 + 2];
  float wpar  = wsf[O_O1 + n*7 + 3];
  float wb    = wsf[O_O1 + n*7 + 4 + c];
  float q0 = wsf[O_O2 + n*4 + 0], q1 = wsf[O_O2 + n*4 + 1];
  float q2 = wsf[O_O2 + n*4 + 2], q3 = wsf[O_O2 + n*4 + 3];
  float den = wsf[O_DEN + n];
  float kn  = (float)wsu[O_KN + n];
  float ce  = fmaxf(wsf[O_CEQ + n], 1.0f);
  float A   = (wsf[O_SGT + n*3 + c] + kn * (wsf[O_SEQ + n*3 + c] / ce)) * (1.0f/(float)TOPK);
  float mnv = 3.4e38f, mxv = -3.4e38f;
  #pragma unroll
  for (int k = 0; k < 4; ++k) {
    int i = k*256 + tid;
    int r = i >> 6, cc = i & 63;
    float xv = xs[r+2][cc+2];
    float blur = hb[r][cc]*g[0] + hb[r+1][cc]*g[1] + hb[r+2][cc]*g[2]
               + hb[r+3][cc]*g[3] + hb[r+4][cc]*g[4];
    blur = clamp01(blur);
    float x4v = clamp01(xv + lamda*(xv - blur));
    float x1v = clamp01(xv*wb);
    float x2v = clamp01(expf(param*logf(xv)) + 0.001f);
    int h = h0 + r, w = w0 + cc;
    float dk = dark[h*WW + w];
    float tr = 1.0f - wpar*dk; tr = tr > 0.1f ? tr : 0.1f;
    float x5v = clamp01((xv - A)/(tr + 0.001f) + A);
    float xsum = (xv + 0.1f*(q0*x1v + q1*x2v + q2*x4v + q3*x5v)) / den;
    out[(size_t)z*HW + (size_t)h*WW + w] = xsum;
    mnv = fminf(mnv, xsum); mxv = fmaxf(mxv, xsum);
  }
  __shared__ float rmn[4], rmx[4];
  #pragma unroll
  for (int off = 32; off; off >>= 1) {
    mnv = fminf(mnv, __shfl_down(mnv, off));
    mxv = fmaxf(mxv, __shfl_down(mxv, off));
  }
  int wave = tid >> 6, lane = tid & 63;
  if (lane == 0) { rmn[wave] = mnv; rmx[wave] = mxv; }
  __syncthreads();
  if (tid == 0) {
    mnv = fminf(fminf(rmn[0], rmn[1]), fminf(rmn[2], rmn[3]));
    mxv = fmaxf(fmaxf(rmx[0], rmx[1]), fmaxf(rmx[2], rmx[3]));
    atomicMin((int*)(wsu + O_MINB + z), __float_as_int(mnv));
    atomicMax((int*)(wsu + O_MAXB + z), __float_as_int(mxv));
  }
}

// ---------------- min-max normalization ----------------
__global__ void k_norm(float* __restrict__ out, const unsigned* __restrict__ wsu) {
  int i4 = blockIdx.x * 256 + threadIdx.x;
  int nc = i4 >> 16;  // 65536 float4 per (n,c)
  float mn = __int_as_float((int)wsu[O_MINB + nc]);
  float mx = __int_as_float((int)wsu[O_MAXB + nc]);
  float sc = 1.0f / (mx - mn + 1e-7f);
  float4 v = ((const float4*)out)[i4];
  v.x = (v.x - mn) * sc; v.y = (v.y - mn) * sc;
  v.z = (v.z - mn) * sc; v.w = (v.w - mn) * sc;
  ((float4*)out)[i4] = v;
}

extern "C" void kernel_launch(void* const* d_in, const int* in_sizes, int n_in,
                              void* d_out, int out_size, void* d_ws, size_t ws_size,
                              hipStream_t stream) {
  const float* x  = (const float*)d_in[0];
  const float* o1 = (const float*)d_in[1];
  const float* o2 = (const float*)d_in[2];
  float* out = (float*)d_out;
  float* wsf = (float*)d_ws;
  unsigned* wsu = (unsigned*)d_ws;
  float* rowsum = out;  // d_out doubles as scratch for rowsum (dead before k_main writes)

  k_params<<<dim3(1), dim3(256), 0, stream>>>(o1, o2, wsf, wsu);
  k_rowsum<<<dim3(512, 16), dim3(256), 0, stream>>>(x, rowsum);
  k_colsum<<<dim3(2, 16, 16), dim3(256), 0, stream>>>(rowsum, wsf);
  for (int pass = 0; pass < 3; ++pass) {
    k_hist<<<dim3(1024), dim3(256), 0, stream>>>(wsf, wsu, pass);
    k_select<<<dim3(16), dim3(256), 0, stream>>>(wsu, pass);
  }
  k_asum<<<dim3(1024), dim3(256), 0, stream>>>(x, wsf, wsu);
  k_main<<<dim3(8, 32, 48), dim3(256), 0, stream>>>(x, wsf, wsu, out);
  k_norm<<<dim3(12288), dim3(256), 0, stream>>>(out, wsu);
}

// Round 2
// 359.712 us; speedup vs baseline: 1.5497x; 1.5497x over previous
//
#include <hip/hip_runtime.h>
#include <math.h>

#define NS   16
#define HH   512
#define WW   512
#define HW   (HH*WW)
#define TOPK 13107
#define NBIN 4096

// ws element offsets (32-bit words)
#define O_O1   0        // [16][7] squashed o1 params
#define O_O2   112      // [16][4] softmax weights
#define O_DEN  176      // [16]    sum(o2)+0.001
#define O_MINB 192      // [48]    per (n,c) min (float bits, int atomics)
#define O_MAXB 240      // [48]
#define O_BSEL 288      // [16]    selected threshold bin (u32)
#define O_KN   304      // [16]    remaining k within threshold bin
#define O_SGT  320      // [16][3] sum x where bin >  bsel
#define O_SEQ  368      // [16][3] sum x where bin == bsel
#define O_CEQ  416      // [16]    count bin == bsel (as float)
#define O_DARK 33280    // [16*512*512] f32 dark channel (same offset as round 1)

__device__ __forceinline__ float tanh01(float v) { return tanhf(v)*0.5f + 0.5f; }
__device__ __forceinline__ float clamp01(float v) { return fminf(fmaxf(v, 0.0f), 1.0f); }
__device__ __forceinline__ int dark_bin(float v) {
  int b = (int)(v * (float)NBIN);
  return b > (NBIN-1) ? (NBIN-1) : (b < 0 ? 0 : b);
}

// ---------------- params + state init + hist zero ----------------
// grid: 65 blocks. block 0: params + small accumulators. blocks 1..64: zero hist.
__global__ void k_params(const float* __restrict__ o1, const float* __restrict__ o2,
                         float* __restrict__ wsf, unsigned* __restrict__ wsu,
                         unsigned* __restrict__ hist) {
  int tid = threadIdx.x;
  if (blockIdx.x > 0) {
    int idx = (blockIdx.x - 1) * 256 + tid;
    for (int i = idx; i < NS*NBIN; i += 64*256) hist[i] = 0u;
    return;
  }
  if (tid < 48) {
    wsu[O_MINB + tid] = 0x7F800000u;  // +inf
    wsu[O_MAXB + tid] = 0u;           // 0.0f
    wsf[O_SGT + tid] = 0.0f;
    wsf[O_SEQ + tid] = 0.0f;
  }
  if (tid < NS) {
    wsf[O_CEQ + tid] = 0.0f;
    int n = tid;
    float p0 = tanh01(o1[n*7+0])*0.25f + 1.0f;
    float p1 = tanh01(o1[n*7+1])*0.9f  + 0.1f;
    float p2 = tanh01(o1[n*7+2])*2.0f;
    float p3 = tanh01(o1[n*7+3]);
    float p4 = tanh01(o1[n*7+4])*0.1f + 0.95f;
    float p5 = tanh01(o1[n*7+5])*0.1f + 0.95f;
    float p6 = tanh01(o1[n*7+6])*0.1f + 0.95f;
    wsf[O_O1+n*7+0]=p0; wsf[O_O1+n*7+1]=p1; wsf[O_O1+n*7+2]=p2; wsf[O_O1+n*7+3]=p3;
    wsf[O_O1+n*7+4]=p4; wsf[O_O1+n*7+5]=p5; wsf[O_O1+n*7+6]=p6;
    float e0 = expf(tanh01(o2[n*4+0]));
    float e1 = expf(tanh01(o2[n*4+1]));
    float e2 = expf(tanh01(o2[n*4+2]));
    float e3 = expf(tanh01(o2[n*4+3]));
    float s = e0+e1+e2+e3;
    float q0 = e0/s, q1 = e1/s, q2 = e2/s, q3 = e3/s;
    wsf[O_O2+n*4+0]=q0; wsf[O_O2+n*4+1]=q1; wsf[O_O2+n*4+2]=q2; wsf[O_O2+n*4+3]=q3;
    wsf[O_DEN+n] = (q0+q1+q2+q3) + 0.001f;
  }
}

// ---------------- minc + horizontal 15-tap box sum ----------------
__global__ void k_rowsum(const float* __restrict__ x, float* __restrict__ rowsum) {
  int h = blockIdx.x, n = blockIdx.y, tid = threadIdx.x;
  __shared__ float m[WW + 14];
  const float* x0 = x + (size_t)(n*3+0)*HW + (size_t)h*WW;
  const float* x1 = x + (size_t)(n*3+1)*HW + (size_t)h*WW;
  const float* x2 = x + (size_t)(n*3+2)*HW + (size_t)h*WW;
  if (tid < 7) { m[tid] = 0.0f; m[519 + tid] = 0.0f; }
  for (int w = tid; w < WW; w += 256)
    m[7 + w] = fminf(fminf(x0[w], x1[w]), x2[w]);
  __syncthreads();
  float* rs = rowsum + (size_t)n*HW + (size_t)h*WW;
  for (int w = tid; w < WW; w += 256) {
    float s = 0.0f;
    #pragma unroll
    for (int j = 0; j < 15; ++j) s += m[w + j];
    rs[w] = s;
  }
}

// ---------------- vertical 15-tap sliding sum -> dark + fused histogram ----------------
__global__ void k_colsum(const float* __restrict__ rowsum, float* __restrict__ wsf,
                         unsigned* __restrict__ hist) {
  int tid = threadIdx.x;
  int w  = blockIdx.x * 256 + tid;
  int h0 = blockIdx.y * 32;
  int n  = blockIdx.z;
  __shared__ unsigned lh[NBIN];
  for (int i = tid; i < NBIN; i += 256) lh[i] = 0u;
  __syncthreads();
  const float* rs = rowsum + (size_t)n*HW;
  float* dk = wsf + O_DARK + (size_t)n*HW;
  float s = 0.0f;
  #pragma unroll
  for (int dh = -7; dh <= 7; ++dh) {
    int h = h0 + dh;
    if (h >= 0 && h < HH) s += rs[h*WW + w];
  }
  for (int h = h0; h < h0 + 32; ++h) {
    float v = s * (1.0f/225.0f);
    dk[h*WW + w] = v;
    atomicAdd(&lh[dark_bin(v)], 1u);
    int ha = h + 8, hr = h - 7;
    float va = (ha < HH) ? rs[ha*WW + w] : 0.0f;
    float vr = (hr >= 0) ? rs[hr*WW + w] : 0.0f;
    s += va - vr;
  }
  __syncthreads();
  unsigned* gh = hist + n*NBIN;
  for (int i = tid; i < NBIN; i += 256) { unsigned v = lh[i]; if (v) atomicAdd(&gh[i], v); }
}

// ---------------- threshold-bin choose (one pass) ----------------
__global__ void k_select(const unsigned* __restrict__ hist, unsigned* __restrict__ wsu) {
  int n = blockIdx.x, tid = threadIdx.x;
  const unsigned* gh = hist + n*NBIN;
  __shared__ unsigned lh[NBIN];
  __shared__ unsigned partial[256];
  for (int i = tid; i < NBIN; i += 256) lh[i] = gh[i];
  __syncthreads();
  const int ch = NBIN / 256;   // 16 bins per thread-chunk
  unsigned ps = 0;
  #pragma unroll
  for (int j = 0; j < ch; ++j) ps += lh[tid*ch + j];
  partial[tid] = ps;
  __syncthreads();
  if (tid == 0) {
    const unsigned K = TOPK;
    unsigned cum = 0; int bsel = 0;
    for (int t = 255; t >= 0; --t) {
      if (cum + partial[t] >= K) {
        bsel = t*ch;
        for (int b = t*ch + ch - 1; b >= t*ch; --b) {
          if (cum + lh[b] >= K) { bsel = b; break; }
          cum += lh[b];
        }
        break;
      }
      cum += partial[t];
    }
    wsu[O_BSEL + n] = (unsigned)bsel;
    wsu[O_KN + n]   = K - cum;
  }
}

// ---------------- atmospheric-light sums ----------------
__global__ void k_asum(const float* __restrict__ x, float* __restrict__ wsf,
                       const unsigned* __restrict__ wsu) {
  int tid = threadIdx.x;
  int n = blockIdx.x >> 6, chunk = blockIdx.x & 63;
  int bsel = (int)wsu[O_BSEL + n];
  const float* db = wsf + O_DARK + (size_t)n*HW + (size_t)chunk*4096;
  const float* xb = x + (size_t)n*3*HW + (size_t)chunk*4096;
  float s0=0,s1=0,s2=0,e0=0,e1=0,e2=0,ec=0;
  for (int k = 0; k < 16; ++k) {
    int idx = k*256 + tid;
    int b = dark_bin(db[idx]);
    if (b > bsel) {
      s0 += xb[idx]; s1 += xb[HW + idx]; s2 += xb[2*HW + idx];
    } else if (b == bsel) {
      e0 += xb[idx]; e1 += xb[HW + idx]; e2 += xb[2*HW + idx]; ec += 1.0f;
    }
  }
  #pragma unroll
  for (int off = 32; off; off >>= 1) {
    s0 += __shfl_down(s0, off); s1 += __shfl_down(s1, off); s2 += __shfl_down(s2, off);
    e0 += __shfl_down(e0, off); e1 += __shfl_down(e1, off); e2 += __shfl_down(e2, off);
    ec += __shfl_down(ec, off);
  }
  if ((tid & 63) == 0) {
    atomicAdd(&wsf[O_SGT + n*3 + 0], s0);
    atomicAdd(&wsf[O_SGT + n*3 + 1], s1);
    atomicAdd(&wsf[O_SGT + n*3 + 2], s2);
    atomicAdd(&wsf[O_SEQ + n*3 + 0], e0);
    atomicAdd(&wsf[O_SEQ + n*3 + 1], e1);
    atomicAdd(&wsf[O_SEQ + n*3 + 2], e2);
    atomicAdd(&wsf[O_CEQ + n], ec);
  }
}

// ---------------- fused per-pixel kernel ----------------
__global__ void __launch_bounds__(256)
k_main(const float* __restrict__ x, float* __restrict__ wsf,
       unsigned* __restrict__ wsu, float* __restrict__ out) {
  int tid = threadIdx.x;
  int w0 = blockIdx.x * 64, h0 = blockIdx.y * 16;
  int z = blockIdx.z, n = z / 3, c = z % 3;
  const float* dark = wsf + O_DARK + (size_t)n*HW;
  const float* xc = x + (size_t)z*HW;
  __shared__ float xs[20][68];
  __shared__ float hb[20][64];
  for (int i = tid; i < 20*68; i += 256) {
    int r = i / 68, cc = i - r*68;
    int gh = h0 - 2 + r, gw = w0 - 2 + cc;
    float v = 0.0f;
    if (gh >= 0 && gh < HH && gw >= 0 && gw < WW) v = xc[gh*WW + gw];
    xs[r][cc] = v;
  }
  float g[5];
  {
    float s = 0.0f;
    #pragma unroll
    for (int j = 0; j < 5; ++j) { float d = (float)(j-2); g[j] = expf(-0.5f*d*d); s += g[j]; }
    s += 0.001f;
    #pragma unroll
    for (int j = 0; j < 5; ++j) g[j] /= s;
  }
  __syncthreads();
  for (int i = tid; i < 20*64; i += 256) {
    int r = i >> 6, cc = i & 63;
    hb[r][cc] = xs[r][cc]*g[0] + xs[r][cc+1]*g[1] + xs[r][cc+2]*g[2]
              + xs[r][cc+3]*g[3] + xs[r][cc+4]*g[4];
  }
  __syncthreads();
  float param = wsf[O_O1 + n*7 + 0];
  float lamda = wsf[O_O1 + n*7 + 2];
  float wpar  = wsf[O_O1 + n*7 + 3];
  float wb    = wsf[O_O1 + n*7 + 4 + c];
  float q0 = wsf[O_O2 + n*4 + 0], q1 = wsf[O_O2 + n*4 + 1];
  float q2 = wsf[O_O2 + n*4 + 2], q3 = wsf[O_O2 + n*4 + 3];
  float den = wsf[O_DEN + n];
  float kn  = (float)wsu[O_KN + n];
  float ce  = fmaxf(wsf[O_CEQ + n], 1.0f);
  float A   = (wsf[O_SGT + n*3 + c] + kn * (wsf[O_SEQ + n*3 + c] / ce)) * (1.0f/(float)TOPK);
  float mnv = 3.4e38f, mxv = -3.4e38f;
  #pragma unroll
  for (int k = 0; k < 4; ++k) {
    int i = k*256 + tid;
    int r = i >> 6, cc = i & 63;
    float xv = xs[r+2][cc+2];
    float blur = hb[r][cc]*g[0] + hb[r+1][cc]*g[1] + hb[r+2][cc]*g[2]
               + hb[r+3][cc]*g[3] + hb[r+4][cc]*g[4];
    blur = clamp01(blur);
    float x4v = clamp01(xv + lamda*(xv - blur));
    float x1v = clamp01(xv*wb);
    float x2v = clamp01(expf(param*logf(xv)) + 0.001f);
    int h = h0 + r, w = w0 + cc;
    float dk = dark[h*WW + w];
    float tr = 1.0f - wpar*dk; tr = tr > 0.1f ? tr : 0.1f;
    float x5v = clamp01((xv - A)/(tr + 0.001f) + A);
    float xsum = (xv + 0.1f*(q0*x1v + q1*x2v + q2*x4v + q3*x5v)) / den;
    out[(size_t)z*HW + (size_t)h*WW + w] = xsum;
    mnv = fminf(mnv, xsum); mxv = fmaxf(mxv, xsum);
  }
  __shared__ float rmn[4], rmx[4];
  #pragma unroll
  for (int off = 32; off; off >>= 1) {
    mnv = fminf(mnv, __shfl_down(mnv, off));
    mxv = fmaxf(mxv, __shfl_down(mxv, off));
  }
  int wave = tid >> 6, lane = tid & 63;
  if (lane == 0) { rmn[wave] = mnv; rmx[wave] = mxv; }
  __syncthreads();
  if (tid == 0) {
    mnv = fminf(fminf(rmn[0], rmn[1]), fminf(rmn[2], rmn[3]));
    mxv = fmaxf(fmaxf(rmx[0], rmx[1]), fmaxf(rmx[2], rmx[3]));
    atomicMin((int*)(wsu + O_MINB + z), __float_as_int(mnv));
    atomicMax((int*)(wsu + O_MAXB + z), __float_as_int(mxv));
  }
}

// ---------------- min-max normalization ----------------
__global__ void k_norm(float* __restrict__ out, const unsigned* __restrict__ wsu) {
  int i4 = blockIdx.x * 256 + threadIdx.x;
  int nc = i4 >> 16;  // 65536 float4 per (n,c)
  float mn = __int_as_float((int)wsu[O_MINB + nc]);
  float mx = __int_as_float((int)wsu[O_MAXB + nc]);
  float sc = 1.0f / (mx - mn + 1e-7f);
  float4 v = ((const float4*)out)[i4];
  v.x = (v.x - mn) * sc; v.y = (v.y - mn) * sc;
  v.z = (v.z - mn) * sc; v.w = (v.w - mn) * sc;
  ((float4*)out)[i4] = v;
}

extern "C" void kernel_launch(void* const* d_in, const int* in_sizes, int n_in,
                              void* d_out, int out_size, void* d_ws, size_t ws_size,
                              hipStream_t stream) {
  const float* x  = (const float*)d_in[0];
  const float* o1 = (const float*)d_in[1];
  const float* o2 = (const float*)d_in[2];
  float* out = (float*)d_out;
  float* wsf = (float*)d_ws;
  unsigned* wsu = (unsigned*)d_ws;
  float* rowsum = out;                                   // d_out[0,16HW): rowsum scratch
  unsigned* hist = (unsigned*)(out + (size_t)16*HW);     // d_out[16HW,+64K words): histogram scratch

  k_params<<<dim3(65), dim3(256), 0, stream>>>(o1, o2, wsf, wsu, hist);
  k_rowsum<<<dim3(512, 16), dim3(256), 0, stream>>>(x, rowsum);
  k_colsum<<<dim3(2, 16, 16), dim3(256), 0, stream>>>(rowsum, wsf, hist);
  k_select<<<dim3(16), dim3(256), 0, stream>>>(hist, wsu);
  k_asum<<<dim3(1024), dim3(256), 0, stream>>>(x, wsf, wsu);
  k_main<<<dim3(8, 32, 48), dim3(256), 0, stream>>>(x, wsf, wsu, out);
  k_norm<<<dim3(12288), dim3(256), 0, stream>>>(out, wsu);
}

// Round 3
// 206.196 us; speedup vs baseline: 2.7035x; 1.7445x over previous
//
#include <hip/hip_runtime.h>
#include <math.h>

#define NS   16
#define HH   512
#define WW   512
#define HW   (HH*WW)
#define TOPK 13107
#define NBIN 4096

// ---- ws element offsets (32-bit words). NO ATOMICS EVER TARGET d_ws
// (ws atomics measured catastrophically slow: r1 k_hist 148us, r2 k_asum/k_main 134us,
//  all with <2% HBM + ~30% VALU — blocks stall holding slots at the final atomic).
#define O_O1   0        // [16][7] squashed o1 params
#define O_O2   112      // [16][4] softmax weights
#define O_DEN  176      // [16]    sum(o2)+0.001
#define O_BSEL 288      // [16]    selected threshold bin
#define O_KN   304      // [16]    remaining k within threshold bin
#define O_A    320      // [16][3] atmospheric light
#define O_MIN  368      // [48]    final per-(n,c) min
#define O_MAX  416      // [48]    final per-(n,c) max
#define O_MMP  512      // [48][512] per-block min(0:256)/max(256:512) partials
#define O_DARK 33280    // [16*512*512] f32 dark channel

// ---- d_out scratch layout (words; all dead before k_main writes out):
//   [0, 16HW)            rowsum
//   [16HW, 16HW+65536)   histogram 16x4096
//   [17HW, 17HW+8192)    k_asum per-block partials 1024 x 8

__device__ __forceinline__ float tanh01(float v) { return tanhf(v)*0.5f + 0.5f; }
__device__ __forceinline__ float clamp01(float v) { return fminf(fmaxf(v, 0.0f), 1.0f); }
__device__ __forceinline__ int dark_bin(float v) {
  int b = (int)(v * (float)NBIN);
  return b > (NBIN-1) ? (NBIN-1) : (b < 0 ? 0 : b);
}

// ---------------- params + hist zero ----------------
__global__ void k_params(const float* __restrict__ o1, const float* __restrict__ o2,
                         float* __restrict__ wsf, unsigned* __restrict__ hist) {
  int tid = threadIdx.x;
  if (blockIdx.x > 0) {
    int idx = (blockIdx.x - 1) * 256 + tid;
    for (int i = idx; i < NS*NBIN; i += 64*256) hist[i] = 0u;
    return;
  }
  if (tid < NS) {
    int n = tid;
    float p0 = tanh01(o1[n*7+0])*0.25f + 1.0f;
    float p1 = tanh01(o1[n*7+1])*0.9f  + 0.1f;
    float p2 = tanh01(o1[n*7+2])*2.0f;
    float p3 = tanh01(o1[n*7+3]);
    float p4 = tanh01(o1[n*7+4])*0.1f + 0.95f;
    float p5 = tanh01(o1[n*7+5])*0.1f + 0.95f;
    float p6 = tanh01(o1[n*7+6])*0.1f + 0.95f;
    wsf[O_O1+n*7+0]=p0; wsf[O_O1+n*7+1]=p1; wsf[O_O1+n*7+2]=p2; wsf[O_O1+n*7+3]=p3;
    wsf[O_O1+n*7+4]=p4; wsf[O_O1+n*7+5]=p5; wsf[O_O1+n*7+6]=p6;
    float e0 = expf(tanh01(o2[n*4+0]));
    float e1 = expf(tanh01(o2[n*4+1]));
    float e2 = expf(tanh01(o2[n*4+2]));
    float e3 = expf(tanh01(o2[n*4+3]));
    float s = e0+e1+e2+e3;
    float q0 = e0/s, q1 = e1/s, q2 = e2/s, q3 = e3/s;
    wsf[O_O2+n*4+0]=q0; wsf[O_O2+n*4+1]=q1; wsf[O_O2+n*4+2]=q2; wsf[O_O2+n*4+3]=q3;
    wsf[O_DEN+n] = (q0+q1+q2+q3) + 0.001f;
  }
}

// ---------------- minc + horizontal 15-tap box sum ----------------
__global__ void k_rowsum(const float* __restrict__ x, float* __restrict__ rowsum) {
  int h = blockIdx.x, n = blockIdx.y, tid = threadIdx.x;
  __shared__ float m[WW + 14];
  const float* x0 = x + (size_t)(n*3+0)*HW + (size_t)h*WW;
  const float* x1 = x + (size_t)(n*3+1)*HW + (size_t)h*WW;
  const float* x2 = x + (size_t)(n*3+2)*HW + (size_t)h*WW;
  if (tid < 7) { m[tid] = 0.0f; m[519 + tid] = 0.0f; }
  for (int w = tid; w < WW; w += 256)
    m[7 + w] = fminf(fminf(x0[w], x1[w]), x2[w]);
  __syncthreads();
  float* rs = rowsum + (size_t)n*HW + (size_t)h*WW;
  for (int w = tid; w < WW; w += 256) {
    float s = 0.0f;
    #pragma unroll
    for (int j = 0; j < 15; ++j) s += m[w + j];
    rs[w] = s;
  }
}

// ---------------- vertical 15-tap sliding sum -> dark + fused histogram ----------------
__global__ void k_colsum(const float* __restrict__ rowsum, float* __restrict__ wsf,
                         unsigned* __restrict__ hist) {
  int tid = threadIdx.x;
  int w  = blockIdx.x * 256 + tid;
  int h0 = blockIdx.y * 32;
  int n  = blockIdx.z;
  __shared__ unsigned lh[NBIN];
  for (int i = tid; i < NBIN; i += 256) lh[i] = 0u;
  __syncthreads();
  const float* rs = rowsum + (size_t)n*HW;
  float* dk = wsf + O_DARK + (size_t)n*HW;
  float s = 0.0f;
  #pragma unroll
  for (int dh = -7; dh <= 7; ++dh) {
    int h = h0 + dh;
    if (h >= 0 && h < HH) s += rs[h*WW + w];
  }
  for (int h = h0; h < h0 + 32; ++h) {
    float v = s * (1.0f/225.0f);
    dk[h*WW + w] = v;
    atomicAdd(&lh[dark_bin(v)], 1u);
    int ha = h + 8, hr = h - 7;
    float va = (ha < HH) ? rs[ha*WW + w] : 0.0f;
    float vr = (hr >= 0) ? rs[hr*WW + w] : 0.0f;
    s += va - vr;
  }
  __syncthreads();
  unsigned* gh = hist + n*NBIN;  // d_out scratch: atomics here are fast (measured r2)
  for (int i = tid; i < NBIN; i += 256) { unsigned v = lh[i]; if (v) atomicAdd(&gh[i], v); }
}

// ---------------- threshold-bin choose ----------------
__global__ void k_select(const unsigned* __restrict__ hist, unsigned* __restrict__ wsu) {
  int n = blockIdx.x, tid = threadIdx.x;
  const unsigned* gh = hist + n*NBIN;
  __shared__ unsigned lh[NBIN];
  __shared__ unsigned partial[256];
  for (int i = tid; i < NBIN; i += 256) lh[i] = gh[i];
  __syncthreads();
  const int ch = NBIN / 256;
  unsigned ps = 0;
  #pragma unroll
  for (int j = 0; j < ch; ++j) ps += lh[tid*ch + j];
  partial[tid] = ps;
  __syncthreads();
  if (tid == 0) {
    const unsigned K = TOPK;
    unsigned cum = 0; int bsel = 0;
    for (int t = 255; t >= 0; --t) {
      if (cum + partial[t] >= K) {
        bsel = t*ch;
        for (int b = t*ch + ch - 1; b >= t*ch; --b) {
          if (cum + lh[b] >= K) { bsel = b; break; }
          cum += lh[b];
        }
        break;
      }
      cum += partial[t];
    }
    wsu[O_BSEL + n] = (unsigned)bsel;   // plain stores to ws: fine
    wsu[O_KN + n]   = K - cum;
  }
}

// ---------------- atmospheric-light partial sums (branchless, no atomics) ----------------
__global__ void k_asum(const float* __restrict__ x, const float* __restrict__ wsf,
                       const unsigned* __restrict__ wsu, float* __restrict__ part) {
  int tid = threadIdx.x;
  int n = blockIdx.x >> 6, chunk = blockIdx.x & 63;
  int bsel = (int)wsu[O_BSEL + n];
  const float* db = wsf + O_DARK + (size_t)n*HW + (size_t)chunk*4096;
  const float* xb = x + (size_t)n*3*HW + (size_t)chunk*4096;
  float s0=0,s1=0,s2=0,e0=0,e1=0,e2=0,ec=0;
  for (int k = 0; k < 16; ++k) {
    int idx = k*256 + tid;
    int b = dark_bin(db[idx]);
    float v0 = xb[idx], v1 = xb[HW + idx], v2 = xb[2*HW + idx];
    bool gt = (b > bsel), eq = (b == bsel);
    s0 += gt ? v0 : 0.0f; s1 += gt ? v1 : 0.0f; s2 += gt ? v2 : 0.0f;
    e0 += eq ? v0 : 0.0f; e1 += eq ? v1 : 0.0f; e2 += eq ? v2 : 0.0f;
    ec += eq ? 1.0f : 0.0f;
  }
  #pragma unroll
  for (int off = 32; off; off >>= 1) {
    s0 += __shfl_down(s0, off); s1 += __shfl_down(s1, off); s2 += __shfl_down(s2, off);
    e0 += __shfl_down(e0, off); e1 += __shfl_down(e1, off); e2 += __shfl_down(e2, off);
    ec += __shfl_down(ec, off);
  }
  __shared__ float bl[4][7];
  int wave = tid >> 6, lane = tid & 63;
  if (lane == 0) {
    bl[wave][0]=s0; bl[wave][1]=s1; bl[wave][2]=s2;
    bl[wave][3]=e0; bl[wave][4]=e1; bl[wave][5]=e2; bl[wave][6]=ec;
  }
  __syncthreads();
  if (tid < 7) {
    float v = bl[0][tid] + bl[1][tid] + bl[2][tid] + bl[3][tid];
    part[blockIdx.x*8 + tid] = v;   // plain store to d_out scratch
  }
}

// ---------------- fold partials -> A per (n,c) ----------------
__global__ void k_areduce(const float* __restrict__ part, const unsigned* __restrict__ wsu,
                          float* __restrict__ wsf) {
  int n = blockIdx.x, t = threadIdx.x;  // 64 threads = 64 chunks
  const float* p = part + (size_t)(n*64 + t)*8;
  float s0=p[0], s1=p[1], s2=p[2], e0=p[3], e1=p[4], e2=p[5], ec=p[6];
  #pragma unroll
  for (int off = 32; off; off >>= 1) {
    s0 += __shfl_down(s0, off); s1 += __shfl_down(s1, off); s2 += __shfl_down(s2, off);
    e0 += __shfl_down(e0, off); e1 += __shfl_down(e1, off); e2 += __shfl_down(e2, off);
    ec += __shfl_down(ec, off);
  }
  if (t == 0) {
    float kn = (float)wsu[O_KN + n];
    float ce = fmaxf(ec, 1.0f);
    wsf[O_A + n*3 + 0] = (s0 + kn * (e0 / ce)) * (1.0f/(float)TOPK);
    wsf[O_A + n*3 + 1] = (s1 + kn * (e1 / ce)) * (1.0f/(float)TOPK);
    wsf[O_A + n*3 + 2] = (s2 + kn * (e2 / ce)) * (1.0f/(float)TOPK);
  }
}

// ---------------- fused per-pixel kernel (no atomics) ----------------
__global__ void __launch_bounds__(256)
k_main(const float* __restrict__ x, float* __restrict__ wsf, float* __restrict__ out) {
  int tid = threadIdx.x;
  int w0 = blockIdx.x * 64, h0 = blockIdx.y * 16;
  int z = blockIdx.z, n = z / 3, c = z % 3;
  const float* dark = wsf + O_DARK + (size_t)n*HW;
  const float* xc = x + (size_t)z*HW;
  __shared__ float xs[20][68];
  __shared__ float hb[20][64];
  for (int i = tid; i < 20*68; i += 256) {
    int r = i / 68, cc = i - r*68;
    int gh = h0 - 2 + r, gw = w0 - 2 + cc;
    float v = 0.0f;
    if (gh >= 0 && gh < HH && gw >= 0 && gw < WW) v = xc[gh*WW + gw];
    xs[r][cc] = v;
  }
  float g[5];
  {
    float s = 0.0f;
    #pragma unroll
    for (int j = 0; j < 5; ++j) { float d = (float)(j-2); g[j] = __expf(-0.5f*d*d); s += g[j]; }
    s += 0.001f;
    #pragma unroll
    for (int j = 0; j < 5; ++j) g[j] /= s;
  }
  __syncthreads();
  for (int i = tid; i < 20*64; i += 256) {
    int r = i >> 6, cc = i & 63;
    hb[r][cc] = xs[r][cc]*g[0] + xs[r][cc+1]*g[1] + xs[r][cc+2]*g[2]
              + xs[r][cc+3]*g[3] + xs[r][cc+4]*g[4];
  }
  __syncthreads();
  float param = wsf[O_O1 + n*7 + 0];
  float lamda = wsf[O_O1 + n*7 + 2];
  float wpar  = wsf[O_O1 + n*7 + 3];
  float wb    = wsf[O_O1 + n*7 + 4 + c];
  float q0 = wsf[O_O2 + n*4 + 0], q1 = wsf[O_O2 + n*4 + 1];
  float q2 = wsf[O_O2 + n*4 + 2], q3 = wsf[O_O2 + n*4 + 3];
  float den = wsf[O_DEN + n];
  float A   = wsf[O_A + n*3 + c];
  float mnv = 3.4e38f, mxv = -3.4e38f;
  #pragma unroll
  for (int k = 0; k < 4; ++k) {
    int i = k*256 + tid;
    int r = i >> 6, cc = i & 63;
    float xv = xs[r+2][cc+2];
    float blur = hb[r][cc]*g[0] + hb[r+1][cc]*g[1] + hb[r+2][cc]*g[2]
               + hb[r+3][cc]*g[3] + hb[r+4][cc]*g[4];
    blur = clamp01(blur);
    float x4v = clamp01(xv + lamda*(xv - blur));
    float x1v = clamp01(xv*wb);
    float x2v = clamp01(__expf(param*__logf(xv)) + 0.001f);
    int h = h0 + r, w = w0 + cc;
    float dk = dark[h*WW + w];
    float tr = 1.0f - wpar*dk; tr = tr > 0.1f ? tr : 0.1f;
    float x5v = clamp01((xv - A)/(tr + 0.001f) + A);
    float xsum = (xv + 0.1f*(q0*x1v + q1*x2v + q2*x4v + q3*x5v)) / den;
    out[(size_t)z*HW + (size_t)h*WW + w] = xsum;
    mnv = fminf(mnv, xsum); mxv = fmaxf(mxv, xsum);
  }
  __shared__ float rmn[4], rmx[4];
  #pragma unroll
  for (int off = 32; off; off >>= 1) {
    mnv = fminf(mnv, __shfl_down(mnv, off));
    mxv = fmaxf(mxv, __shfl_down(mxv, off));
  }
  int wave = tid >> 6, lane = tid & 63;
  if (lane == 0) { rmn[wave] = mnv; rmx[wave] = mxv; }
  __syncthreads();
  if (tid == 0) {
    mnv = fminf(fminf(rmn[0], rmn[1]), fminf(rmn[2], rmn[3]));
    mxv = fmaxf(fmaxf(rmx[0], rmx[1]), fmaxf(rmx[2], rmx[3]));
    int bxy = blockIdx.y * 8 + blockIdx.x;        // 0..255
    wsf[O_MMP + z*512 + bxy]       = mnv;          // plain stores
    wsf[O_MMP + z*512 + 256 + bxy] = mxv;
  }
}

// ---------------- fold min/max partials ----------------
__global__ void k_mmred(float* __restrict__ wsf) {
  int z = blockIdx.x, tid = threadIdx.x;
  float mn = wsf[O_MMP + z*512 + tid];
  float mx = wsf[O_MMP + z*512 + 256 + tid];
  #pragma unroll
  for (int off = 32; off; off >>= 1) {
    mn = fminf(mn, __shfl_down(mn, off));
    mx = fmaxf(mx, __shfl_down(mx, off));
  }
  __shared__ float rmn[4], rmx[4];
  int wave = tid >> 6, lane = tid & 63;
  if (lane == 0) { rmn[wave] = mn; rmx[wave] = mx; }
  __syncthreads();
  if (tid == 0) {
    wsf[O_MIN + z] = fminf(fminf(rmn[0], rmn[1]), fminf(rmn[2], rmn[3]));
    wsf[O_MAX + z] = fmaxf(fmaxf(rmx[0], rmx[1]), fmaxf(rmx[2], rmx[3]));
  }
}

// ---------------- min-max normalization ----------------
__global__ void k_norm(float* __restrict__ out, const float* __restrict__ wsf) {
  int i4 = blockIdx.x * 256 + threadIdx.x;
  int nc = i4 >> 16;
  float mn = wsf[O_MIN + nc];
  float mx = wsf[O_MAX + nc];
  float sc = 1.0f / (mx - mn + 1e-7f);
  float4 v = ((const float4*)out)[i4];
  v.x = (v.x - mn) * sc; v.y = (v.y - mn) * sc;
  v.z = (v.z - mn) * sc; v.w = (v.w - mn) * sc;
  ((float4*)out)[i4] = v;
}

extern "C" void kernel_launch(void* const* d_in, const int* in_sizes, int n_in,
                              void* d_out, int out_size, void* d_ws, size_t ws_size,
                              hipStream_t stream) {
  const float* x  = (const float*)d_in[0];
  const float* o1 = (const float*)d_in[1];
  const float* o2 = (const float*)d_in[2];
  float* out = (float*)d_out;
  float* wsf = (float*)d_ws;
  unsigned* wsu = (unsigned*)d_ws;
  float* rowsum = out;                                   // d_out[0,16HW)
  unsigned* hist = (unsigned*)(out + (size_t)16*HW);     // d_out[16HW,+64K words)
  float* part = out + (size_t)17*HW;                     // d_out[17HW,+8192 words)

  k_params<<<dim3(65), dim3(256), 0, stream>>>(o1, o2, wsf, hist);
  k_rowsum<<<dim3(512, 16), dim3(256), 0, stream>>>(x, rowsum);
  k_colsum<<<dim3(2, 16, 16), dim3(256), 0, stream>>>(rowsum, wsf, hist);
  k_select<<<dim3(16), dim3(256), 0, stream>>>(hist, wsu);
  k_asum<<<dim3(1024), dim3(256), 0, stream>>>(x, wsf, wsu, part);
  k_areduce<<<dim3(16), dim3(64), 0, stream>>>(part, wsu, wsf);
  k_main<<<dim3(8, 32, 48), dim3(256), 0, stream>>>(x, wsf, out);
  k_mmred<<<dim3(48), dim3(256), 0, stream>>>(wsf);
  k_norm<<<dim3(12288), dim3(256), 0, stream>>>(out, wsf);
}

// Round 4
// 192.104 us; speedup vs baseline: 2.9018x; 1.0734x over previous
//
#include <hip/hip_runtime.h>
#include <math.h>

#define NS   16
#define HH   512
#define WW   512
#define HW   (HH*WW)
#define TOPK 13107
#define NBIN 4096

// ---- ws word offsets. NO ATOMICS EVER TARGET d_ws (measured 100+us stalls r1/r2).
#define O_O1   0        // [16][7] squashed o1 params
#define O_O2   112      // [16][4] softmax weights
#define O_DEN  176      // [16]    sum(o2)+0.001
#define O_KN   304      // [16]    remaining k within threshold bin
#define O_A    320      // [16][3] atmospheric light
#define O_MMP  512      // [48][512] per-block min(0:256)/max(256:512) partials
#define O_DARK 33280    // [16*512*512] f32 dark channel

// ---- d_out scratch (words; dead before k_main overwrites):
//   [16HW, 16HW+65536)   histogram 16x4096   (atomics OK here — d_out, measured fast)
//   [17HW, 17HW+8192)    k_asum per-block partials 1024 x 8

// Gaussian weights phi/(sum+0.001), hardcoded (double-derived; ref fp32 diff ~1e-8)
#define G0 0.054466787f
#define G1 0.244103071f
#define G2 0.402457854f

__device__ __forceinline__ float tanh01(float v) { return tanhf(v)*0.5f + 0.5f; }
__device__ __forceinline__ float clamp01(float v) { return fminf(fmaxf(v, 0.0f), 1.0f); }
__device__ __forceinline__ int dark_bin(float v) {
  int b = (int)(v * (float)NBIN);
  return b > (NBIN-1) ? (NBIN-1) : (b < 0 ? 0 : b);
}

// ---------------- zero histogram ----------------
__global__ void k_zero(unsigned* __restrict__ hist) {
  int i = blockIdx.x * 256 + threadIdx.x;       // 16384 uint4 = 65536 words
  uint4 z; z.x = 0u; z.y = 0u; z.z = 0u; z.w = 0u;
  ((uint4*)hist)[i] = z;
}

// ---------------- fused minc + 15x15 box filter + histogram ----------------
// block: 64x32 dark tile. grid (8,16,16).
__global__ void __launch_bounds__(256)
k_dark(const float* __restrict__ x, float* __restrict__ wsf, unsigned* __restrict__ hist) {
  __shared__ __align__(16) float sm[4096 + 46*64];   // union(minc[46*80]=3680, lh[4096]) + hsum[46*64]
  float* minc = sm;
  unsigned* lh = (unsigned*)sm;
  float* hsum = sm + 4096;
  int tid = threadIdx.x;
  int w0 = blockIdx.x * 64, h0 = blockIdx.y * 32, n = blockIdx.z;
  const float* xb = x + (size_t)n*3*HW;

  // stage minc rows [h0-7,h0+39) cols [w0-8,w0+72), zero outside (box filter zero-pads)
  for (int i = tid; i < 46*20; i += 256) {
    int r = i / 20, q = i - r*20;
    int hm = h0 - 7 + r, wc = w0 - 8 + 4*q;
    float4 v; v.x = 0.f; v.y = 0.f; v.z = 0.f; v.w = 0.f;
    if (hm >= 0 && hm < HH && wc >= 0 && wc < WW) {
      size_t o = (size_t)hm*WW + wc;
      float4 a = *(const float4*)&xb[o];
      float4 b = *(const float4*)&xb[HW + o];
      float4 c = *(const float4*)&xb[2*HW + o];
      v.x = fminf(fminf(a.x,b.x),c.x); v.y = fminf(fminf(a.y,b.y),c.y);
      v.z = fminf(fminf(a.z,b.z),c.z); v.w = fminf(fminf(a.w,b.w),c.w);
    }
    *(float4*)&minc[r*80 + 4*q] = v;
  }
  __syncthreads();
  // horizontal 15-tap sum: hsum[r][c] = sum minc[r][c+1..c+15]
  for (int i = tid; i < 46*16; i += 256) {
    int r = i >> 4, c4 = (i & 15) * 4;
    const float4* mr = (const float4*)&minc[r*80];
    int qb = c4 >> 2;
    float m[20];
    #pragma unroll
    for (int t = 0; t < 5; ++t) {
      float4 v = mr[qb + t];
      m[4*t] = v.x; m[4*t+1] = v.y; m[4*t+2] = v.z; m[4*t+3] = v.w;
    }
    float s = 0.f;
    #pragma unroll
    for (int j = 1; j <= 15; ++j) s += m[j];
    float4 o;
    o.x = s; s += m[16] - m[1];
    o.y = s; s += m[17] - m[2];
    o.z = s; s += m[18] - m[3];
    o.w = s;
    *(float4*)&hsum[r*64 + c4] = o;
  }
  __syncthreads();
  for (int i = tid; i < NBIN; i += 256) lh[i] = 0u;   // minc dead; reuse as hist
  __syncthreads();
  // vertical 15-tap sliding sum -> dark + bin
  {
    int c = tid & 63, ty = tid >> 6, r0 = ty * 8;
    float s = 0.f;
    #pragma unroll
    for (int j = 0; j < 15; ++j) s += hsum[(r0 + j)*64 + c];
    float* dk = wsf + O_DARK + (size_t)n*HW;
    #pragma unroll
    for (int i = 0; i < 8; ++i) {
      int r = r0 + i;
      float v = s * (1.0f/225.0f);
      dk[(size_t)(h0 + r)*WW + w0 + c] = v;
      atomicAdd(&lh[dark_bin(v)], 1u);
      if (i < 7) s += hsum[(r + 15)*64 + c] - hsum[r*64 + c];
    }
  }
  __syncthreads();
  unsigned* gh = hist + n*NBIN;
  for (int i = tid; i < NBIN; i += 256) { unsigned v = lh[i]; if (v) atomicAdd(&gh[i], v); }
}

// ---------------- select (redundant per block) + atmospheric partial sums ----------------
__global__ void __launch_bounds__(256)
k_asum(const float* __restrict__ x, const float* __restrict__ wsf,
       const unsigned* __restrict__ hist, unsigned* __restrict__ wsu,
       float* __restrict__ part) {
  __shared__ __align__(16) unsigned lh[NBIN];
  __shared__ unsigned spp[256];
  __shared__ int sh_bsel; __shared__ unsigned sh_kn;
  __shared__ float bl[4][7];
  int tid = threadIdx.x;
  int n = blockIdx.x >> 6, chunk = blockIdx.x & 63;
  // load hist (L2-resident) + per-thread partial of 16 bins
  const uint4* gh4 = (const uint4*)(hist + n*NBIN);
  unsigned ps = 0;
  #pragma unroll
  for (int k = 0; k < 4; ++k) {
    uint4 v = gh4[tid*4 + k];
    *(uint4*)&lh[tid*16 + 4*k] = v;
    ps += v.x + v.y + v.z + v.w;
  }
  spp[tid] = ps;
  __syncthreads();
  if (tid == 0) {
    const unsigned K = TOPK;
    unsigned cum = 0; int bsel = 0;
    for (int t = 255; t >= 0; --t) {
      if (cum + spp[t] >= K) {
        bsel = t*16;
        for (int b = t*16 + 15; b >= t*16; --b) {
          if (cum + lh[b] >= K) { bsel = b; break; }
          cum += lh[b];
        }
        break;
      }
      cum += spp[t];
    }
    sh_bsel = bsel; sh_kn = K - cum;
    if (chunk == 0) wsu[O_KN + n] = K - cum;   // plain store to ws
  }
  __syncthreads();
  int bsel = sh_bsel;
  // branchless f4 partial sums over this 4096-element chunk
  const float4* db = (const float4*)(wsf + O_DARK + (size_t)n*HW + (size_t)chunk*4096);
  const float4* x0 = (const float4*)(x + (size_t)n*3*HW + (size_t)chunk*4096);
  const float4* x1 = x0 + HW/4;
  const float4* x2 = x0 + HW/2;
  float s0=0,s1=0,s2=0,e0=0,e1=0,e2=0,ec=0;
  #pragma unroll
  for (int k = 0; k < 4; ++k) {
    int idx = k*256 + tid;
    float4 d = db[idx], a = x0[idx], b = x1[idx], c = x2[idx];
    #define ACC(DX, AX, BX, CX) { \
      int bb = dark_bin(DX); \
      bool gt = (bb > bsel), eq = (bb == bsel); \
      s0 += gt ? AX : 0.f; s1 += gt ? BX : 0.f; s2 += gt ? CX : 0.f; \
      e0 += eq ? AX : 0.f; e1 += eq ? BX : 0.f; e2 += eq ? CX : 0.f; \
      ec += eq ? 1.f : 0.f; }
    ACC(d.x, a.x, b.x, c.x) ACC(d.y, a.y, b.y, c.y)
    ACC(d.z, a.z, b.z, c.z) ACC(d.w, a.w, b.w, c.w)
    #undef ACC
  }
  #pragma unroll
  for (int off = 32; off; off >>= 1) {
    s0 += __shfl_down(s0, off); s1 += __shfl_down(s1, off); s2 += __shfl_down(s2, off);
    e0 += __shfl_down(e0, off); e1 += __shfl_down(e1, off); e2 += __shfl_down(e2, off);
    ec += __shfl_down(ec, off);
  }
  int wave = tid >> 6, lane = tid & 63;
  if (lane == 0) {
    bl[wave][0]=s0; bl[wave][1]=s1; bl[wave][2]=s2;
    bl[wave][3]=e0; bl[wave][4]=e1; bl[wave][5]=e2; bl[wave][6]=ec;
  }
  __syncthreads();
  if (tid < 7) {
    float v = bl[0][tid] + bl[1][tid] + bl[2][tid] + bl[3][tid];
    part[blockIdx.x*8 + tid] = v;   // plain store to d_out scratch
  }
}

// ---------------- fold partials -> A, plus param squashing ----------------
__global__ void k_areduce(const float* __restrict__ part, const unsigned* __restrict__ wsu,
                          float* __restrict__ wsf, const float* __restrict__ o1,
                          const float* __restrict__ o2) {
  int n = blockIdx.x, t = threadIdx.x;  // 64 threads = 64 chunks
  const float* p = part + (size_t)(n*64 + t)*8;
  float s0=p[0], s1=p[1], s2=p[2], e0=p[3], e1=p[4], e2=p[5], ec=p[6];
  #pragma unroll
  for (int off = 32; off; off >>= 1) {
    s0 += __shfl_down(s0, off); s1 += __shfl_down(s1, off); s2 += __shfl_down(s2, off);
    e0 += __shfl_down(e0, off); e1 += __shfl_down(e1, off); e2 += __shfl_down(e2, off);
    ec += __shfl_down(ec, off);
  }
  if (t == 0) {
    float kn = (float)wsu[O_KN + n];
    float ce = fmaxf(ec, 1.0f);
    wsf[O_A + n*3 + 0] = (s0 + kn * (e0 / ce)) * (1.0f/(float)TOPK);
    wsf[O_A + n*3 + 1] = (s1 + kn * (e1 / ce)) * (1.0f/(float)TOPK);
    wsf[O_A + n*3 + 2] = (s2 + kn * (e2 / ce)) * (1.0f/(float)TOPK);
    // params (needed only by k_main, which follows)
    wsf[O_O1+n*7+0] = tanh01(o1[n*7+0])*0.25f + 1.0f;
    wsf[O_O1+n*7+1] = tanh01(o1[n*7+1])*0.9f  + 0.1f;
    wsf[O_O1+n*7+2] = tanh01(o1[n*7+2])*2.0f;
    wsf[O_O1+n*7+3] = tanh01(o1[n*7+3]);
    wsf[O_O1+n*7+4] = tanh01(o1[n*7+4])*0.1f + 0.95f;
    wsf[O_O1+n*7+5] = tanh01(o1[n*7+5])*0.1f + 0.95f;
    wsf[O_O1+n*7+6] = tanh01(o1[n*7+6])*0.1f + 0.95f;
    float q0 = expf(tanh01(o2[n*4+0]));
    float q1 = expf(tanh01(o2[n*4+1]));
    float q2 = expf(tanh01(o2[n*4+2]));
    float q3 = expf(tanh01(o2[n*4+3]));
    float s = q0+q1+q2+q3;
    q0 /= s; q1 /= s; q2 /= s; q3 /= s;
    wsf[O_O2+n*4+0]=q0; wsf[O_O2+n*4+1]=q1; wsf[O_O2+n*4+2]=q2; wsf[O_O2+n*4+3]=q3;
    wsf[O_DEN+n] = (q0+q1+q2+q3) + 0.001f;
  }
}

// ---------------- fused per-pixel kernel, float4 per thread ----------------
__global__ void __launch_bounds__(256)
k_main(const float* __restrict__ x, float* __restrict__ wsf, float* __restrict__ out) {
  __shared__ __align__(16) float xs[20*72];   // rows h0-2..h0+17, cols w0-4..w0+67
  __shared__ __align__(16) float hb[20*64];   // horizontal blur
  __shared__ float rmn[4], rmx[4];
  int tid = threadIdx.x;
  int w0 = blockIdx.x * 64, h0 = blockIdx.y * 16;
  int z = blockIdx.z, n = z / 3, c = z % 3;
  const float* xc = x + (size_t)z*HW;
  for (int i = tid; i < 360; i += 256) {
    int r = i / 18, q = i - r*18;
    int gh = h0 - 2 + r, gw = w0 - 4 + 4*q;
    float4 v; v.x = 0.f; v.y = 0.f; v.z = 0.f; v.w = 0.f;
    if (gh >= 0 && gh < HH && gw >= 0 && gw < WW)
      v = *(const float4*)&xc[(size_t)gh*WW + gw];
    *(float4*)&xs[r*72 + 4*q] = v;
  }
  __syncthreads();
  // horizontal 5-tap: hb[r][cL] = sum g[j]*xs[r][cL+2+j]
  for (int i = tid; i < 320; i += 256) {
    int r = i >> 4, c4 = (i & 15) * 4;
    const float4* xr = (const float4*)&xs[r*72];
    int qb = c4 >> 2;
    float4 A4 = xr[qb], B4 = xr[qb+1], C4 = xr[qb+2];
    float m2=A4.z, m3=A4.w, m4=B4.x, m5=B4.y, m6=B4.z, m7=B4.w, m8=C4.x, m9=C4.y;
    float4 o;
    o.x = G0*(m2+m6) + G1*(m3+m5) + G2*m4;
    o.y = G0*(m3+m7) + G1*(m4+m6) + G2*m5;
    o.z = G0*(m4+m8) + G1*(m5+m7) + G2*m6;
    o.w = G0*(m5+m9) + G1*(m6+m8) + G2*m7;
    *(float4*)&hb[r*64 + c4] = o;
  }
  __syncthreads();
  float param = wsf[O_O1 + n*7 + 0];
  float lamda = wsf[O_O1 + n*7 + 2];
  float wpar  = wsf[O_O1 + n*7 + 3];
  float wb    = wsf[O_O1 + n*7 + 4 + c];
  float q0 = wsf[O_O2 + n*4 + 0], q1 = wsf[O_O2 + n*4 + 1];
  float q2 = wsf[O_O2 + n*4 + 2], q3 = wsf[O_O2 + n*4 + 3];
  float rden = 1.0f / wsf[O_DEN + n];
  float A   = wsf[O_A + n*3 + c];
  int r = tid >> 4, c4 = (tid & 15) * 4;
  float4 xv = *(const float4*)&xs[(r+2)*72 + c4 + 4];
  float4 b0 = *(const float4*)&hb[(r+0)*64 + c4];
  float4 b1 = *(const float4*)&hb[(r+1)*64 + c4];
  float4 b2 = *(const float4*)&hb[(r+2)*64 + c4];
  float4 b3 = *(const float4*)&hb[(r+3)*64 + c4];
  float4 b4 = *(const float4*)&hb[(r+4)*64 + c4];
  const float* dark = wsf + O_DARK + (size_t)n*HW;
  float4 dk = *(const float4*)&dark[(size_t)(h0+r)*WW + w0 + c4];
  float4 osum;
  float mnv = 3.4e38f, mxv = -3.4e38f;
  #define PIX(OX, XV, B0, B1, B2, B3, B4, DK) { \
    float blur = clamp01(G0*(B0+B4) + G1*(B1+B3) + G2*B2); \
    float x4v = clamp01(XV + lamda*(XV - blur)); \
    float x1v = clamp01(XV * wb); \
    float x2v = clamp01(__expf(param*__logf(XV)) + 0.001f); \
    float tr = 1.0f - wpar*DK; tr = tr > 0.1f ? tr : 0.1f; \
    float x5v = clamp01((XV - A)/(tr + 0.001f) + A); \
    OX = (XV + 0.1f*(q0*x1v + q1*x2v + q2*x4v + q3*x5v)) * rden; \
    mnv = fminf(mnv, OX); mxv = fmaxf(mxv, OX); }
  PIX(osum.x, xv.x, b0.x, b1.x, b2.x, b3.x, b4.x, dk.x)
  PIX(osum.y, xv.y, b0.y, b1.y, b2.y, b3.y, b4.y, dk.y)
  PIX(osum.z, xv.z, b0.z, b1.z, b2.z, b3.z, b4.z, dk.z)
  PIX(osum.w, xv.w, b0.w, b1.w, b2.w, b3.w, b4.w, dk.w)
  #undef PIX
  *(float4*)&out[(size_t)z*HW + (size_t)(h0+r)*WW + w0 + c4] = osum;
  #pragma unroll
  for (int off = 32; off; off >>= 1) {
    mnv = fminf(mnv, __shfl_down(mnv, off));
    mxv = fmaxf(mxv, __shfl_down(mxv, off));
  }
  int wave = tid >> 6, lane = tid & 63;
  if (lane == 0) { rmn[wave] = mnv; rmx[wave] = mxv; }
  __syncthreads();
  if (tid == 0) {
    mnv = fminf(fminf(rmn[0], rmn[1]), fminf(rmn[2], rmn[3]));
    mxv = fmaxf(fmaxf(rmx[0], rmx[1]), fmaxf(rmx[2], rmx[3]));
    int bxy = blockIdx.y * 8 + blockIdx.x;
    wsf[O_MMP + z*512 + bxy]       = mnv;   // plain stores to ws
    wsf[O_MMP + z*512 + 256 + bxy] = mxv;
  }
}

// ---------------- min-max reduce (redundant per block) + normalization ----------------
__global__ void __launch_bounds__(256)
k_norm(float* __restrict__ out, const float* __restrict__ wsf) {
  __shared__ float rmn[4], rmx[4];
  int tid = threadIdx.x;
  int nc = blockIdx.x >> 8;   // 256 blocks per (n,c)
  float mn = wsf[O_MMP + nc*512 + tid];
  float mx = wsf[O_MMP + nc*512 + 256 + tid];
  #pragma unroll
  for (int off = 32; off; off >>= 1) {
    mn = fminf(mn, __shfl_down(mn, off));
    mx = fmaxf(mx, __shfl_down(mx, off));
  }
  int wave = tid >> 6, lane = tid & 63;
  if (lane == 0) { rmn[wave] = mn; rmx[wave] = mx; }
  __syncthreads();
  mn = fminf(fminf(rmn[0], rmn[1]), fminf(rmn[2], rmn[3]));
  mx = fmaxf(fmaxf(rmx[0], rmx[1]), fmaxf(rmx[2], rmx[3]));
  float sc = 1.0f / (mx - mn + 1e-7f);
  int i4 = blockIdx.x * 256 + tid;
  float4 v = ((const float4*)out)[i4];
  v.x = (v.x - mn) * sc; v.y = (v.y - mn) * sc;
  v.z = (v.z - mn) * sc; v.w = (v.w - mn) * sc;
  ((float4*)out)[i4] = v;
}

extern "C" void kernel_launch(void* const* d_in, const int* in_sizes, int n_in,
                              void* d_out, int out_size, void* d_ws, size_t ws_size,
                              hipStream_t stream) {
  const float* x  = (const float*)d_in[0];
  const float* o1 = (const float*)d_in[1];
  const float* o2 = (const float*)d_in[2];
  float* out = (float*)d_out;
  float* wsf = (float*)d_ws;
  unsigned* wsu = (unsigned*)d_ws;
  unsigned* hist = (unsigned*)(out + (size_t)16*HW);   // d_out scratch
  float* part = out + (size_t)17*HW;                   // d_out scratch

  k_zero<<<dim3(64), dim3(256), 0, stream>>>(hist);
  k_dark<<<dim3(8, 16, 16), dim3(256), 0, stream>>>(x, wsf, hist);
  k_asum<<<dim3(1024), dim3(256), 0, stream>>>(x, wsf, hist, wsu, part);
  k_areduce<<<dim3(16), dim3(64), 0, stream>>>(part, wsu, wsf, o1, o2);
  k_main<<<dim3(8, 32, 48), dim3(256), 0, stream>>>(x, wsf, out);
  k_norm<<<dim3(12288), dim3(256), 0, stream>>>(out, wsf);
}